// Round 1
// baseline (2357.917 us; speedup 1.0000x reference)
//
#include <hip/hip_runtime.h>

#define NV 500000
#define NE 16000000

// Edge kernel: for each edge e with (s,t):
//   h = ((v[s]‖v[t]) @ We + be) * p[e]   (2 features)
//   msg = h @ Wh + bh                    (3 features)
//   atomicAdd into acc[t][0..2]
__global__ __launch_bounds__(256) void gnn_edge_kernel(
    const float* __restrict__ vertices,   // NV x 3
    const float* __restrict__ prob,       // NE
    const int*   __restrict__ edges,      // NE x 2 (int32)
    const float* __restrict__ We,         // 6 x 2 row-major
    const float* __restrict__ be,         // 2
    const float* __restrict__ Wh,         // 2 x 3 row-major
    const float* __restrict__ bh,         // 3
    float* __restrict__ acc,              // NV x 3 (pre-zeroed)
    int E)
{
    int e = blockIdx.x * blockDim.x + threadIdx.x;
    if (e >= E) return;

    int2 st = ((const int2*)edges)[e];
    int s = st.x;
    int t = st.y;
    float p = prob[e];

    float vs0 = vertices[3*s+0], vs1 = vertices[3*s+1], vs2 = vertices[3*s+2];
    float vt0 = vertices[3*t+0], vt1 = vertices[3*t+1], vt2 = vertices[3*t+2];

    // We is (2*VD=6) x (EF=2), row-major: We[k][f] = We[k*2+f]
    float h0 = be[0] + vs0*We[0] + vs1*We[2] + vs2*We[4]
                     + vt0*We[6] + vt1*We[8] + vt2*We[10];
    float h1 = be[1] + vs0*We[1] + vs1*We[3] + vs2*We[5]
                     + vt0*We[7] + vt1*We[9] + vt2*We[11];
    h0 *= p;
    h1 *= p;

    // Wh is 2 x 3 row-major: msg[d] = h0*Wh[0][d] + h1*Wh[1][d] + bh[d]
    float m0 = bh[0] + h0*Wh[0] + h1*Wh[3];
    float m1 = bh[1] + h0*Wh[1] + h1*Wh[4];
    float m2 = bh[2] + h0*Wh[2] + h1*Wh[5];

    atomicAdd(&acc[3*t+0], m0);
    atomicAdd(&acc[3*t+1], m1);
    atomicAdd(&acc[3*t+2], m2);
}

// Vertex kernel: out[v] = vertices[v] + acc[v] @ Wv + bv   (in place on acc==out)
__global__ __launch_bounds__(256) void gnn_vertex_kernel(
    const float* __restrict__ vertices,   // NV x 3
    const float* __restrict__ Wv,         // 3 x 3 row-major
    const float* __restrict__ bv,         // 3
    float* __restrict__ out,              // NV x 3 (holds acc on entry)
    int n)
{
    int v = blockIdx.x * blockDim.x + threadIdx.x;
    if (v >= n) return;

    float h0 = out[3*v+0];
    float h1 = out[3*v+1];
    float h2 = out[3*v+2];

    // (h @ Wv)[d] = sum_k h[k] * Wv[k*3+d]
    float o0 = vertices[3*v+0] + bv[0] + h0*Wv[0] + h1*Wv[3] + h2*Wv[6];
    float o1 = vertices[3*v+1] + bv[1] + h0*Wv[1] + h1*Wv[4] + h2*Wv[7];
    float o2 = vertices[3*v+2] + bv[2] + h0*Wv[2] + h1*Wv[5] + h2*Wv[8];

    out[3*v+0] = o0;
    out[3*v+1] = o1;
    out[3*v+2] = o2;
}

extern "C" void kernel_launch(void* const* d_in, const int* in_sizes, int n_in,
                              void* d_out, int out_size, void* d_ws, size_t ws_size,
                              hipStream_t stream)
{
    const float* vertices = (const float*)d_in[0];
    const float* prob     = (const float*)d_in[1];
    const int*   edges    = (const int*)d_in[2];
    const float* We       = (const float*)d_in[3];
    const float* be       = (const float*)d_in[4];
    const float* Wh       = (const float*)d_in[5];
    const float* bh       = (const float*)d_in[6];
    const float* Wv       = (const float*)d_in[7];
    const float* bv       = (const float*)d_in[8];
    float* out = (float*)d_out;

    const int E = in_sizes[2] / 2;   // edges is (E,2)
    const int n = in_sizes[0] / 3;   // vertices is (N,3)

    // Zero the accumulator (d_out) — harness poisons it, we must re-init every call.
    hipMemsetAsync(d_out, 0, (size_t)out_size * sizeof(float), stream);

    int eblocks = (E + 255) / 256;
    gnn_edge_kernel<<<eblocks, 256, 0, stream>>>(vertices, prob, edges,
                                                 We, be, Wh, bh, out, E);

    int vblocks = (n + 255) / 256;
    gnn_vertex_kernel<<<vblocks, 256, 0, stream>>>(vertices, Wv, bv, out, n);
}